// Round 7
// baseline (371.977 us; speedup 1.0000x reference)
//
#include <hip/hip_runtime.h>
#include <hip/hip_bf16.h>

typedef unsigned int u32;
typedef unsigned short u16;
typedef __attribute__((ext_vector_type(8))) short short8;   // 8 bf16 (4 VGPRs)
typedef __attribute__((ext_vector_type(4))) float f32x4;    // MFMA C/D
typedef __attribute__((ext_vector_type(2))) float f32x2;    // v_pk_fma_f32 operand

#define N_PTS 100000
#define NSAMP 16

__device__ __forceinline__ float lo2f(u32 u){ return __uint_as_float(u << 16); }
__device__ __forceinline__ float hi2f(u32 u){ return __uint_as_float(u & 0xffff0000u); }
__device__ __forceinline__ float us2f(u16 u){ return __uint_as_float(((u32)u) << 16); }

// round-to-nearest-even f32 -> bf16 bits (finite values only)
__device__ __forceinline__ u16 f2bf(float f) {
    u32 u = __float_as_uint(f);
    return (u16)((u + 0x7fffu + ((u >> 16) & 1u)) >> 16);
}
__device__ __forceinline__ u32 pack2(float k, float v) {
    return (u32)f2bf(k) | ((u32)f2bf(v) << 16);
}

// wave-local LDS RAW fence: waits for this wave's outstanding DS ops.
// Valid ONLY because every LDS buffer slice is owned by a single wave.
#define WAVE_LDS_FENCE() asm volatile("s_waitcnt lgkmcnt(0)" ::: "memory")

// Runtime input-dtype probe (must be called by ALL threads of the block).
__device__ __forceinline__ bool detect_f32(const u16* __restrict__ xprobe) {
    float f = us2f(xprobe[(threadIdx.x & 63) * 2]);
    int cnt = __syncthreads_count(fabsf(f) > 1024.0f ? 1 : 0);
    return cnt >= 8;
}

// canonical fp32 weight-block offsets (floats, each 16B-aligned)
#define OFF_WQ   0
#define OFF_BQ   4096
#define OFF_WK   4160
#define OFF_BK   8256
#define OFF_WV   8320
#define OFF_BV   12416
#define OFF_WP1  12480
#define OFF_BP1  12492
#define OFF_GP   12496
#define OFF_BP   12500
#define OFF_WP2  12504
#define OFF_BP2  12696
#define OFF_G1   12760
#define OFF_BB1  12824
#define OFF_WA   12888
#define OFF_BA   13400
#define OFF_G2   13408
#define OFF_BB2  13416
#define OFF_WB   13424
#define OFF_BW   13488
#define FRAG_OFF 13504   /* bf16 frag blob: 2 planes x 12288 u16 = 12288 floats */
#define OFF_WAT  25792   /* WaT[s][c] : 8 x 64 f32 (transposed Wa)  */
#define OFF_WBT  26304   /* WbT[t][s] : 8 x 8  f32 (transposed Wb)  */
#define CW_PAD   32768   /* pad region to 128 KB of floats */

// ---------------------------------------------------------------------------
// K0: canonicalize weights to fp32 + build pre-transposed bf16 hi/lo MFMA
// B-fragment blob (for QKV) + WaT/WbT fp32 transposed blobs (for attn).
// ---------------------------------------------------------------------------
__global__ __launch_bounds__(256) void convert_kernel(
    const u16* __restrict__ xprobe,
    const void* s0,  const void* s1,  const void* s2,  const void* s3,
    const void* s4,  const void* s5,  const void* s6,  const void* s7,
    const void* s8,  const void* s9,  const void* s10, const void* s11,
    const void* s12, const void* s13, const void* s14, const void* s15,
    const void* s16, const void* s17, const void* s18, const void* s19,
    float* __restrict__ cw)
{
    bool isf32 = detect_f32(xprobe);
    const void* srcs[20] = {s0,s1,s2,s3,s4,s5,s6,s7,s8,s9,s10,s11,s12,s13,s14,s15,s16,s17,s18,s19};
    const int sizes[20] = {4096,64,4096,64,4096,64,9,3,3,3,192,64,64,64,512,8,8,8,64,8};
    const int offs[20]  = {OFF_WQ,OFF_BQ,OFF_WK,OFF_BK,OFF_WV,OFF_BV,OFF_WP1,OFF_BP1,OFF_GP,OFF_BP,
                           OFF_WP2,OFF_BP2,OFF_G1,OFF_BB1,OFF_WA,OFF_BA,OFF_G2,OFF_BB2,OFF_WB,OFF_BW};
    int tid = threadIdx.x + blockIdx.x * 256;
    int stride = gridDim.x * 256;
    for (int a = 0; a < 20; a++) {
        const void* s = srcs[a];
        for (int k = tid; k < sizes[a]; k += stride)
            cw[offs[a] + k] = isf32 ? ((const float*)s)[k] : us2f(((const u16*)s)[k]);
    }

    // MFMA B-frag blob (reads raw weight srcs directly)
    u16* fb = (u16*)(cw + FRAG_OFF);
    for (int t = tid; t < 24576; t += stride) {
        int plane = t / 12288, r = t - plane * 12288;
        int m  = r >> 12;
        int r2 = r & 4095;
        int kh = r2 >> 11;
        int r3 = r2 & 2047;
        int w  = r3 >> 9;
        int r4 = r3 & 511;
        int l  = r4 >> 3, j = r4 & 7;
        int k  = kh * 32 + (l >> 4) * 8 + j;
        int nc = w * 16 + (l & 15);
        int si = k * 64 + nc;
        const void* s = (m == 0) ? s0 : ((m == 1) ? s2 : s4);
        float val = isf32 ? ((const float*)s)[si] : us2f(((const u16*)s)[si]);
        u16 hb = f2bf(val);
        fb[t] = (plane == 0) ? hb : f2bf(val - us2f(hb));
    }

    // WaT[s][c] = Wa[c][s] ; WbT[t][s] = Wb[s][t]
    for (int t = tid; t < 512 + 64; t += stride) {
        if (t < 512) {
            int s = t >> 6, cc = t & 63;
            int si = cc * 8 + s;
            cw[OFF_WAT + s * 64 + cc] = isf32 ? ((const float*)s14)[si] : us2f(((const u16*)s14)[si]);
        } else {
            int r = t - 512;
            int tt = r >> 3, ss = r & 7;
            int si = ss * 8 + tt;
            cw[OFF_WBT + tt * 8 + ss] = isf32 ? ((const float*)s18)[si] : us2f(((const u16*)s18)[si]);
        }
    }
}

// ---------------------------------------------------------------------------
// K1: MFMA QKV projection (unchanged from round 4 — passing).
// ---------------------------------------------------------------------------
#define QKV_TPB 5
__global__ __launch_bounds__(256) void qkv_mfma_kernel(
    const u16* __restrict__ xraw, const float* __restrict__ cw,
    float* __restrict__ Q, u32* __restrict__ KV)
{
    bool isf32 = detect_f32(xraw);
    const int w   = threadIdx.x >> 6;
    const int l   = threadIdx.x & 63;
    const int col = l & 15;
    const int g   = l >> 4;

    const u16* fbh = (const u16*)(cw + FRAG_OFF);
    const u16* fbl = fbh + 12288;
    short8 bh[3][2], bl[3][2];
#pragma unroll
    for (int m = 0; m < 3; m++)
#pragma unroll
        for (int kh = 0; kh < 2; kh++) {
            int o = (((m * 2 + kh) * 4 + w) * 64 + l) * 8;
            bh[m][kh] = *(const short8*)(fbh + o);
            bl[m][kh] = *(const short8*)(fbl + o);
        }
    const float bqc = cw[OFF_BQ + w * 16 + col];
    const float bkc = cw[OFF_BK + w * 16 + col];
    const float bvc = cw[OFF_BV + w * 16 + col];

#define LOAD_A(IT, AH, AL)                                                        \
    {                                                                             \
        const int M0_ = (blockIdx.x * QKV_TPB + (IT)) * 16;                       \
        if (isf32) {                                                              \
            const float4* xf = (const float4*)xraw;                               \
            _Pragma("unroll")                                                     \
            for (int kh = 0; kh < 2; kh++) {                                      \
                float4 f0 = xf[(size_t)(M0_ + col) * 16 + kh * 8 + g * 2];        \
                float4 f1 = xf[(size_t)(M0_ + col) * 16 + kh * 8 + g * 2 + 1];    \
                float ff[8] = {f0.x, f0.y, f0.z, f0.w, f1.x, f1.y, f1.z, f1.w};   \
                _Pragma("unroll")                                                 \
                for (int j = 0; j < 8; j++) {                                     \
                    u16 hb_ = f2bf(ff[j]);                                        \
                    AH[kh][j] = (short)hb_;                                       \
                    AL[kh][j] = (short)f2bf(ff[j] - us2f(hb_));                   \
                }                                                                 \
            }                                                                     \
        } else {                                                                  \
            const short8* xb = (const short8*)xraw;                               \
            _Pragma("unroll")                                                     \
            for (int kh = 0; kh < 2; kh++)                                        \
                AH[kh] = xb[(size_t)(M0_ + col) * 8 + kh * 4 + g];                \
        }                                                                         \
    }

    short8 ahA[2], alA[2], ahB[2], alB[2];
    LOAD_A(0, ahA, alA);

#pragma unroll
    for (int it = 0; it < QKV_TPB; it++) {
        short8 (&ah)[2] = (it & 1) ? ahB : ahA;
        short8 (&al)[2] = (it & 1) ? alB : alA;
        short8 (&ahN)[2] = (it & 1) ? ahA : ahB;
        short8 (&alN)[2] = (it & 1) ? alA : alB;
        if (it + 1 < QKV_TPB) LOAD_A(it + 1, ahN, alN);

        const int M0 = (blockIdx.x * QKV_TPB + it) * 16;
        f32x4 aQ = {bqc, bqc, bqc, bqc};
        f32x4 aK = {bkc, bkc, bkc, bkc};
        f32x4 aV = {bvc, bvc, bvc, bvc};

#pragma unroll
        for (int kh = 0; kh < 2; kh++) {
            aQ = __builtin_amdgcn_mfma_f32_16x16x32_bf16(ah[kh], bh[0][kh], aQ, 0, 0, 0);
            aK = __builtin_amdgcn_mfma_f32_16x16x32_bf16(ah[kh], bh[1][kh], aK, 0, 0, 0);
            aV = __builtin_amdgcn_mfma_f32_16x16x32_bf16(ah[kh], bh[2][kh], aV, 0, 0, 0);
            aQ = __builtin_amdgcn_mfma_f32_16x16x32_bf16(ah[kh], bl[0][kh], aQ, 0, 0, 0);
            aK = __builtin_amdgcn_mfma_f32_16x16x32_bf16(ah[kh], bl[1][kh], aK, 0, 0, 0);
            aV = __builtin_amdgcn_mfma_f32_16x16x32_bf16(ah[kh], bl[2][kh], aV, 0, 0, 0);
            if (isf32) {
                aQ = __builtin_amdgcn_mfma_f32_16x16x32_bf16(al[kh], bh[0][kh], aQ, 0, 0, 0);
                aK = __builtin_amdgcn_mfma_f32_16x16x32_bf16(al[kh], bh[1][kh], aK, 0, 0, 0);
                aV = __builtin_amdgcn_mfma_f32_16x16x32_bf16(al[kh], bh[2][kh], aV, 0, 0, 0);
            }
        }

#pragma unroll
        for (int r = 0; r < 4; r++) {
            int row = M0 + g * 4 + r;
            Q [(size_t)row * 64 + w * 16 + col] = aQ[r];
            KV[(size_t)row * 64 + w * 16 + col] = pack2(aK[r], aV[r]);
        }
    }
#undef LOAD_A
}

// ---------------------------------------------------------------------------
// K2: fused attention — barrier-free (round-6 structure) + two changes:
//  (1) LOAD BURST: every global load (16 KV gathers, Q, P, all weight
//      scalars) is issued before one s_waitcnt vmcnt(0) + sched_barrier(0);
//      the "memory" clobber stops the compiler sinking loads below it, so
//      ~30 VMEM ops are in flight per wave (round-6 regression showed the
//      compiler had serialized the gathers at VGPR=40).
//  (2) stages 2/3/5 accumulate as f32x2 with split accumulators so the
//      compiler can emit v_pk_fma_f32 (2 fma/instr).
// ---------------------------------------------------------------------------
__global__ __launch_bounds__(256) void attn_kernel(
    const u16* __restrict__ P, const int* __restrict__ IDX,
    const u16* __restrict__ xprobe, const float* __restrict__ cw,
    const float* __restrict__ Q, const u32* __restrict__ KV,
    void* __restrict__ OUT)
{
    __shared__ __align__(16) float wvbuf[4][NSAMP * 68];  // relu(bn1(w)), stride 68
    __shared__ __align__(16) float tbbuf[4][NSAMP * 8];   // relu(bn2(.@Wa+ba))
    __shared__ __align__(16) float w2buf[4][NSAMP * 8];   // softmax weights
    __shared__ __align__(16) float hbuf[4][NSAMP * 4];    // h[n][d], d<3 used

    bool isf32 = detect_f32(xprobe);

    const int pt = threadIdx.x >> 6;
    const int c  = threadIdx.x & 63;
    const int i  = blockIdx.x * 4 + pt;        // grid*4 == N_PTS exactly
    const float rs = 1.0f / sqrtf(1.0f + 1e-5f);

    // ================= LOAD BURST (all global loads issued here) ===========
    const int jv = IDX[(size_t)i * NSAMP + (c & 15)];

    u32 kvw[NSAMP];
    const u32* KVc = KV + c;
#pragma unroll
    for (int n = 0; n < NSAMP; n++) {
        int j = __builtin_amdgcn_readlane(jv, n);   // SGPR -> SALU addressing
        kvw[n] = KVc[(size_t)j << 6];
    }

    const float qq = Q[(size_t)i * 64 + c];

    const float* Pf = (const float*)P;
    const int n_p  = c / 3;
    const int d_p  = c - n_p * 3;
    const int np15 = n_p & 15;
    const int j_p  = __shfl(jv, np15, 64);
    float pj, pid;
    if (isf32) { pj = Pf[(size_t)j_p * 3 + d_p]; pid = Pf[(size_t)i * 3 + d_p]; }
    else       { pj = us2f(P[(size_t)j_p * 3 + d_p]); pid = us2f(P[(size_t)i * 3 + d_p]); }

    // per-lane channel constants (issued inside the burst)
    const float wp2c0 = cw[OFF_WP2 + 0 * 64 + c];
    const float wp2c1 = cw[OFF_WP2 + 1 * 64 + c];
    const float wp2c2 = cw[OFF_WP2 + 2 * 64 + c];
    const float bp2c  = cw[OFF_BP2 + c];
    const float g1c   = cw[OFF_G1  + c] * rs;
    const float bb1c  = cw[OFF_BB1 + c];
    // h-MLP per-(d) weights (lanes use d_p)
    const float gd  = cw[OFF_GP + d_p] * rs;
    const float w0s = cw[OFF_WP1 + 0 * 3 + d_p] * gd;
    const float w1s = cw[OFF_WP1 + 1 * 3 + d_p] * gd;
    const float w2s = cw[OFF_WP1 + 2 * 3 + d_p] * gd;
    const float bs  = cw[OFF_BP1 + d_p] * gd + cw[OFF_BP + d_p];

    asm volatile("s_waitcnt vmcnt(0)" ::: "memory");
    __builtin_amdgcn_sched_barrier(0);
    // =======================================================================

    // ---- distributed h-MLP: lane (n,d) = (c/3, c%3) computes h[n][d] ----
    const float pr = pj - pid;
    const int lb = np15 * 3;
    const float prD0 = __shfl(pr, lb + 0, 64);
    const float prD1 = __shfl(pr, lb + 1, 64);
    const float prD2 = __shfl(pr, lb + 2, 64);
    {
        float h = fmaf(prD2, w2s, fmaf(prD1, w1s, fmaf(prD0, w0s, bs)));
        h = fmaxf(h, 0.0f);
        if (c < 48) hbuf[pt][np15 * 4 + d_p] = h;
    }
    WAVE_LDS_FENCE();   // hbuf RAW (same wave)

    float pv[NSAMP];

    // ---- stage 1: per-(n,c) relation input into LDS; v+pe kept in regs ----
#pragma unroll
    for (int n = 0; n < NSAMP; n++) {
        float4 hb = *((const float4*)&hbuf[pt][n * 4]);
        float pe = fmaf(hb.z, wp2c2, fmaf(hb.y, wp2c1, fmaf(hb.x, wp2c0, bp2c)));
        float kk = lo2f(kvw[n]);
        float vv = hi2f(kvw[n]);
        wvbuf[pt][n * 68 + c] = fmaxf(fmaf(kk - qq + pe, g1c, bb1c), 0.0f);
        pv[n] = vv + pe;
    }
    WAVE_LDS_FENCE();   // wvbuf RAW (same wave)

    // ---- stage 2 (merged reps, f32x2 packed): a[n][s], a[n+8][s] ----
    const int s2s = c & 7, s2n = c >> 3;
    f32x2 a0v = {cw[OFF_BA + s2s], 0.0f};
    f32x2 a1v = a0v;
    const float4* waT4 = (const float4*)(cw + OFF_WAT + s2s * 64);
#pragma unroll
    for (int c4 = 0; c4 < 16; c4++) {
        float4 wa  = waT4[c4];
        float4 w40 = *((const float4*)&wvbuf[pt][s2n * 68 + c4 * 4]);
        float4 w41 = *((const float4*)&wvbuf[pt][(s2n + 8) * 68 + c4 * 4]);
        f32x2 waA = {wa.x, wa.y},  waB = {wa.z, wa.w};
        f32x2 p0A = {w40.x, w40.y}, p0B = {w40.z, w40.w};
        f32x2 p1A = {w41.x, w41.y}, p1B = {w41.z, w41.w};
        a0v += p0A * waA;  a0v += p0B * waB;
        a1v += p1A * waA;  a1v += p1B * waB;
    }
    {
        float a0 = a0v.x + a0v.y, a1 = a1v.x + a1v.y;
        float g2s = cw[OFF_G2 + s2s] * rs, bb2s = cw[OFF_BB2 + s2s];
        tbbuf[pt][s2n * 8 + s2s]       = fmaxf(fmaf(a0, g2s, bb2s), 0.0f);
        tbbuf[pt][(s2n + 8) * 8 + s2s] = fmaxf(fmaf(a1, g2s, bb2s), 0.0f);
    }
    WAVE_LDS_FENCE();   // tbbuf RAW (same wave)

    // ---- stage 3 (merged reps, f32x2 packed): logits in registers ----
    f32x2 w2av = {cw[OFF_BW + s2s], 0.0f};
    f32x2 w2bv = w2av;
    {
        float4 wb0 = *(const float4*)(cw + OFF_WBT + s2s * 8);
        float4 wb1 = *(const float4*)(cw + OFF_WBT + s2s * 8 + 4);
        float4 t00 = *((const float4*)&tbbuf[pt][s2n * 8]);
        float4 t01 = *((const float4*)&tbbuf[pt][s2n * 8 + 4]);
        float4 t10 = *((const float4*)&tbbuf[pt][(s2n + 8) * 8]);
        float4 t11 = *((const float4*)&tbbuf[pt][(s2n + 8) * 8 + 4]);
        f32x2 b0 = {wb0.x, wb0.y}, b1 = {wb0.z, wb0.w};
        f32x2 b2 = {wb1.x, wb1.y}, b3 = {wb1.z, wb1.w};
        f32x2 u0 = {t00.x, t00.y}, u1 = {t00.z, t00.w};
        f32x2 u2 = {t01.x, t01.y}, u3 = {t01.z, t01.w};
        f32x2 v0 = {t10.x, t10.y}, v1 = {t10.z, t10.w};
        f32x2 v2 = {t11.x, t11.y}, v3 = {t11.z, t11.w};
        w2av += u0 * b0;  w2av += u1 * b1;  w2av += u2 * b2;  w2av += u3 * b3;
        w2bv += v0 * b0;  w2bv += v1 * b1;  w2bv += v2 * b2;  w2bv += v3 * b3;
    }
    float w2a = w2av.x + w2av.y;
    float w2b = w2bv.x + w2bv.y;

    // ---- stage 4: softmax over n per channel t, straight from registers ----
    {
        float m = fmaxf(w2a, w2b);
        m = fmaxf(m, __shfl_xor(m, 8, 64));
        m = fmaxf(m, __shfl_xor(m, 16, 64));
        m = fmaxf(m, __shfl_xor(m, 32, 64));
        float e0 = __expf(w2a - m), e1 = __expf(w2b - m);
        float s = e0 + e1;
        s += __shfl_xor(s, 8, 64);
        s += __shfl_xor(s, 16, 64);
        s += __shfl_xor(s, 32, 64);
        float inv = 1.0f / s;
        w2buf[pt][s2n * 8 + s2s]       = e0 * inv;
        w2buf[pt][(s2n + 8) * 8 + s2s] = e1 * inv;
    }
    WAVE_LDS_FENCE();   // w2buf RAW (same wave)

    // ---- stage 5: out[c] = sum_n pv[n] * w[n][c&7]  (f32x2 packed) ----
    f32x2 ov = {0.0f, 0.0f};
#pragma unroll
    for (int n = 0; n < NSAMP; n += 2) {
        f32x2 pvp = {pv[n], pv[n + 1]};
        f32x2 wp  = {w2buf[pt][n * 8 + s2s], w2buf[pt][(n + 1) * 8 + s2s]};
        ov += pvp * wp;
    }
    float o = ov.x + ov.y;
    if (isf32) ((float*)OUT)[(size_t)i * 64 + c] = o;
    else       ((__hip_bfloat16*)OUT)[(size_t)i * 64 + c] = __float2bfloat16(o);
}

// ---------------------------------------------------------------------------
extern "C" void kernel_launch(void* const* d_in, const int* in_sizes, int n_in,
                              void* d_out, int out_size, void* d_ws, size_t ws_size,
                              hipStream_t stream)
{
    const u16* p   = (const u16*)d_in[0];
    const u16* x   = (const u16*)d_in[1];
    const int* idx = (const int*)d_in[2];

    // workspace layout: cw 128KB + Q 25.6MB + KV 25.6MB ≈ 51.4 MB
    float* cw = (float*)d_ws;                   // 128 KB (incl. blobs)
    float* Q  = cw + CW_PAD;                    // N*64 f32 = 25.6 MB
    u32*   KV = (u32*)(Q + (size_t)N_PTS * 64); // N*64 u32 = 25.6 MB

    convert_kernel<<<16, 256, 0, stream>>>(
        x,
        d_in[3],  d_in[4],  d_in[5],  d_in[6],  d_in[7],  d_in[8],
        d_in[9],  d_in[10], d_in[11], d_in[12], d_in[13], d_in[14],
        d_in[15], d_in[16], d_in[17], d_in[18], d_in[19], d_in[20],
        d_in[21], d_in[22], cw);
    qkv_mfma_kernel<<<1250, 256, 0, stream>>>(x, cw, Q, KV);  // 1250*5*16 = 100000
    attn_kernel<<<N_PTS / 4, 256, 0, stream>>>(p, idx, x, cw, Q, KV, d_out);
}

// Round 8
// 360.941 us; speedup vs baseline: 1.0306x; 1.0306x over previous
//
#include <hip/hip_runtime.h>
#include <hip/hip_bf16.h>

typedef unsigned int u32;
typedef unsigned short u16;
typedef __attribute__((ext_vector_type(8))) short short8;   // 8 bf16 (4 VGPRs)
typedef __attribute__((ext_vector_type(4))) float f32x4;    // MFMA C/D
typedef __attribute__((ext_vector_type(2))) float f32x2;    // v_pk_fma_f32 operand

#define N_PTS 100000
#define NSAMP 16

__device__ __forceinline__ float lo2f(u32 u){ return __uint_as_float(u << 16); }
__device__ __forceinline__ float hi2f(u32 u){ return __uint_as_float(u & 0xffff0000u); }
__device__ __forceinline__ float us2f(u16 u){ return __uint_as_float(((u32)u) << 16); }

// round-to-nearest-even f32 -> bf16 bits (finite values only)
__device__ __forceinline__ u16 f2bf(float f) {
    u32 u = __float_as_uint(f);
    return (u16)((u + 0x7fffu + ((u >> 16) & 1u)) >> 16);
}
__device__ __forceinline__ u32 pack2(float k, float v) {
    return (u32)f2bf(k) | ((u32)f2bf(v) << 16);
}

// wave-local LDS RAW fence (validated round 4)
#define WAVE_LDS_FENCE() asm volatile("s_waitcnt lgkmcnt(0)" ::: "memory")

// Runtime input-dtype probe (must be called by ALL threads of the block).
__device__ __forceinline__ bool detect_f32(const u16* __restrict__ xprobe) {
    float f = us2f(xprobe[(threadIdx.x & 63) * 2]);
    int cnt = __syncthreads_count(fabsf(f) > 1024.0f ? 1 : 0);
    return cnt >= 8;
}

// generic raw-weight element load (fp32 or bf16 source)
__device__ __forceinline__ float rawf(const void* s, int i, bool isf32) {
    return isf32 ? ((const float*)s)[i] : us2f(((const u16*)s)[i]);
}

// canonical fp32 weight-block offsets (floats) — written by qkv block 0,
// consumed by attn (stream-ordered).
#define OFF_WP1  0
#define OFF_BP1  12
#define OFF_GP   16
#define OFF_BP   20
#define OFF_WP2  24
#define OFF_BP2  216
#define OFF_G1   280
#define OFF_BB1  344
#define OFF_BA   408
#define OFF_G2   416
#define OFF_BB2  424
#define OFF_BW   432
#define OFF_WAT  448     /* WaT[s][c] : 8 x 64 f32 (transposed Wa) */
#define OFF_WBT  960     /* WbT[t][s] : 8 x 8  f32 (transposed Wb) */
#define CW_PAD   4096    /* pad to 16 KB of floats */

// ---------------------------------------------------------------------------
// K1: MFMA QKV projection + (block 0) attn-weight canonicalization.
// B-frags built per-block from raw srcs (R3 pattern, proven). hi/lo split:
//   bf16 in :  x@Wh + x@Wl ; fp32 in : xh@Wh + xh@Wl + xl@Wh
// A/B share k-mapping k=(l>>4)*8+j (cancels); C/D: col=l&15, row=(l>>4)*4+r.
// Grid 1250 x 5 tiles x 16 rows = 100000 exactly.
// ---------------------------------------------------------------------------
#define QKV_TPB 5
__global__ __launch_bounds__(256) void qkv_mfma_kernel(
    const u16* __restrict__ xraw,
    const void* s0,  const void* s1,  const void* s2,  const void* s3,
    const void* s4,  const void* s5,  const void* s6,  const void* s7,
    const void* s8,  const void* s9,  const void* s10, const void* s11,
    const void* s12, const void* s13, const void* s14, const void* s15,
    const void* s16, const void* s17, const void* s18, const void* s19,
    float* __restrict__ cw,
    float* __restrict__ Q, u32* __restrict__ KV)
{
    bool isf32 = detect_f32(xraw);
    const int w   = threadIdx.x >> 6;
    const int l   = threadIdx.x & 63;
    const int col = l & 15;
    const int g   = l >> 4;

    // ---- block 0: write attn's canonical weight block (13.5 KB) ----
    if (blockIdx.x == 0) {
        const void* srcs[14] = {s6,s7,s8,s9,s10,s11,s12,s13,s15,s16,s17,s19, s14,s18};
        const int   sizes[14]= {9,3,3,3,192,64,64,64,8,8,8,8, 0,0};
        const int   offs[14] = {OFF_WP1,OFF_BP1,OFF_GP,OFF_BP,OFF_WP2,OFF_BP2,
                                OFF_G1,OFF_BB1,OFF_BA,OFF_G2,OFF_BB2,OFF_BW, 0,0};
        int tid = threadIdx.x;
        for (int a = 0; a < 12; a++)
            for (int k = tid; k < sizes[a]; k += 256)
                cw[offs[a] + k] = rawf(srcs[a], k, isf32);
        // WaT[s][c] = Wa[c][s] ; WbT[t][s] = Wb[s][t]
        for (int t = tid; t < 512 + 64; t += 256) {
            if (t < 512) {
                int s = t >> 6, cc = t & 63;
                cw[OFF_WAT + s * 64 + cc] = rawf(s14, cc * 8 + s, isf32);
            } else {
                int r = t - 512;
                int tt = r >> 3, ss = r & 7;
                cw[OFF_WBT + tt * 8 + ss] = rawf(s18, ss * 8 + tt, isf32);
            }
        }
    }

    // ---- build B fragments (weights) in registers: hi/lo bf16 planes ----
    const void* wsrc[3] = {s0, s2, s4};
    short8 bh[3][2], bl[3][2];
#pragma unroll
    for (int m = 0; m < 3; m++)
#pragma unroll
        for (int kh = 0; kh < 2; kh++)
#pragma unroll
            for (int j = 0; j < 8; j++) {
                float wv_ = rawf(wsrc[m], (kh * 32 + g * 8 + j) * 64 + w * 16 + col, isf32);
                u16 hb = f2bf(wv_);
                bh[m][kh][j] = (short)hb;
                bl[m][kh][j] = (short)f2bf(wv_ - us2f(hb));
            }
    const float bqc = rawf(s1, w * 16 + col, isf32);
    const float bkc = rawf(s3, w * 16 + col, isf32);
    const float bvc = rawf(s5, w * 16 + col, isf32);

#define LOAD_A(IT, AH, AL)                                                        \
    {                                                                             \
        const int M0_ = (blockIdx.x * QKV_TPB + (IT)) * 16;                       \
        if (isf32) {                                                              \
            const float4* xf = (const float4*)xraw;                               \
            _Pragma("unroll")                                                     \
            for (int kh = 0; kh < 2; kh++) {                                      \
                float4 f0 = xf[(size_t)(M0_ + col) * 16 + kh * 8 + g * 2];        \
                float4 f1 = xf[(size_t)(M0_ + col) * 16 + kh * 8 + g * 2 + 1];    \
                float ff[8] = {f0.x, f0.y, f0.z, f0.w, f1.x, f1.y, f1.z, f1.w};   \
                _Pragma("unroll")                                                 \
                for (int j = 0; j < 8; j++) {                                     \
                    u16 hb_ = f2bf(ff[j]);                                        \
                    AH[kh][j] = (short)hb_;                                       \
                    AL[kh][j] = (short)f2bf(ff[j] - us2f(hb_));                   \
                }                                                                 \
            }                                                                     \
        } else {                                                                  \
            const short8* xb = (const short8*)xraw;                               \
            _Pragma("unroll")                                                     \
            for (int kh = 0; kh < 2; kh++)                                        \
                AH[kh] = xb[(size_t)(M0_ + col) * 8 + kh * 4 + g];                \
        }                                                                         \
    }

    short8 ahA[2], alA[2], ahB[2], alB[2];
    LOAD_A(0, ahA, alA);

#pragma unroll
    for (int it = 0; it < QKV_TPB; it++) {
        short8 (&ah)[2] = (it & 1) ? ahB : ahA;
        short8 (&al)[2] = (it & 1) ? alB : alA;
        short8 (&ahN)[2] = (it & 1) ? ahA : ahB;
        short8 (&alN)[2] = (it & 1) ? alA : alB;
        if (it + 1 < QKV_TPB) LOAD_A(it + 1, ahN, alN);

        const int M0 = (blockIdx.x * QKV_TPB + it) * 16;
        f32x4 aQ = {bqc, bqc, bqc, bqc};
        f32x4 aK = {bkc, bkc, bkc, bkc};
        f32x4 aV = {bvc, bvc, bvc, bvc};

#pragma unroll
        for (int kh = 0; kh < 2; kh++) {
            aQ = __builtin_amdgcn_mfma_f32_16x16x32_bf16(ah[kh], bh[0][kh], aQ, 0, 0, 0);
            aK = __builtin_amdgcn_mfma_f32_16x16x32_bf16(ah[kh], bh[1][kh], aK, 0, 0, 0);
            aV = __builtin_amdgcn_mfma_f32_16x16x32_bf16(ah[kh], bh[2][kh], aV, 0, 0, 0);
            aQ = __builtin_amdgcn_mfma_f32_16x16x32_bf16(ah[kh], bl[0][kh], aQ, 0, 0, 0);
            aK = __builtin_amdgcn_mfma_f32_16x16x32_bf16(ah[kh], bl[1][kh], aK, 0, 0, 0);
            aV = __builtin_amdgcn_mfma_f32_16x16x32_bf16(ah[kh], bl[2][kh], aV, 0, 0, 0);
            if (isf32) {
                aQ = __builtin_amdgcn_mfma_f32_16x16x32_bf16(al[kh], bh[0][kh], aQ, 0, 0, 0);
                aK = __builtin_amdgcn_mfma_f32_16x16x32_bf16(al[kh], bh[1][kh], aK, 0, 0, 0);
                aV = __builtin_amdgcn_mfma_f32_16x16x32_bf16(al[kh], bh[2][kh], aV, 0, 0, 0);
            }
        }

#pragma unroll
        for (int r = 0; r < 4; r++) {
            int row = M0 + g * 4 + r;
            Q [(size_t)row * 64 + w * 16 + col] = aQ[r];
            KV[(size_t)row * 64 + w * 16 + col] = pack2(aK[r], aV[r]);
        }
    }
#undef LOAD_A
}

// ---------------------------------------------------------------------------
// K2: fused attention. Round-8: back to the round-4-best barrier structure
// (barrier-free R6/R7 regressed: compiler targeted 36-40 VGPR and spilled the
// gather burst). __launch_bounds__(256,4) allows 128 VGPR so the 16-deep
// gather burst stays register-resident. Keeps: load burst above vmcnt(0),
// merged stage-2/3 reps, WaT/WbT float4 weight loads, pk-fma, register
// logits -> shfl_xor softmax.
// ---------------------------------------------------------------------------
__global__ __launch_bounds__(256, 4) void attn_kernel(
    const u16* __restrict__ P, const int* __restrict__ IDX,
    const u16* __restrict__ xprobe, const float* __restrict__ cw,
    const float* __restrict__ Q, const u32* __restrict__ KV,
    void* __restrict__ OUT)
{
    __shared__ __align__(16) float wvbuf[4][NSAMP * 68];  // relu(bn1(w)), stride 68
    __shared__ __align__(16) float tbbuf[4][NSAMP * 8];   // relu(bn2(.@Wa+ba))
    __shared__ __align__(16) float w2buf[4][NSAMP * 8];   // softmax weights
    __shared__ __align__(16) float hbuf[4][NSAMP * 4];    // h[n][d], d<3 used

    bool isf32 = detect_f32(xprobe);

    const int pt = threadIdx.x >> 6;
    const int c  = threadIdx.x & 63;
    const int i  = blockIdx.x * 4 + pt;        // grid*4 == N_PTS exactly
    const float rs = 1.0f / sqrtf(1.0f + 1e-5f);

    // ================= LOAD BURST (all global loads issued here) ===========
    const int jv = IDX[(size_t)i * NSAMP + (c & 15)];

    u32 kvw[NSAMP];
    const u32* KVc = KV + c;
#pragma unroll
    for (int n = 0; n < NSAMP; n++) {
        int j = __builtin_amdgcn_readlane(jv, n);   // SGPR -> SALU addressing
        kvw[n] = KVc[(size_t)j << 6];
    }

    const float qq = Q[(size_t)i * 64 + c];

    const float* Pf = (const float*)P;
    const int n_p  = c / 3;
    const int d_p  = c - n_p * 3;
    const int np15 = n_p & 15;
    const int j_p  = __shfl(jv, np15, 64);
    float pj, pid;
    if (isf32) { pj = Pf[(size_t)j_p * 3 + d_p]; pid = Pf[(size_t)i * 3 + d_p]; }
    else       { pj = us2f(P[(size_t)j_p * 3 + d_p]); pid = us2f(P[(size_t)i * 3 + d_p]); }

    // per-lane channel constants (issued inside the burst)
    const float wp2c0 = cw[OFF_WP2 + 0 * 64 + c];
    const float wp2c1 = cw[OFF_WP2 + 1 * 64 + c];
    const float wp2c2 = cw[OFF_WP2 + 2 * 64 + c];
    const float bp2c  = cw[OFF_BP2 + c];
    const float g1c   = cw[OFF_G1  + c] * rs;
    const float bb1c  = cw[OFF_BB1 + c];
    const float gd  = cw[OFF_GP + d_p] * rs;
    const float w0s = cw[OFF_WP1 + 0 * 3 + d_p] * gd;
    const float w1s = cw[OFF_WP1 + 1 * 3 + d_p] * gd;
    const float w2s = cw[OFF_WP1 + 2 * 3 + d_p] * gd;
    const float bs  = cw[OFF_BP1 + d_p] * gd + cw[OFF_BP + d_p];

    asm volatile("s_waitcnt vmcnt(0)" ::: "memory");
    __builtin_amdgcn_sched_barrier(0);
    // =======================================================================

    // ---- distributed h-MLP: lane (n,d) = (c/3, c%3) computes h[n][d] ----
    const float pr = pj - pid;
    const int lb = np15 * 3;
    const float prD0 = __shfl(pr, lb + 0, 64);
    const float prD1 = __shfl(pr, lb + 1, 64);
    const float prD2 = __shfl(pr, lb + 2, 64);
    {
        float h = fmaf(prD2, w2s, fmaf(prD1, w1s, fmaf(prD0, w0s, bs)));
        h = fmaxf(h, 0.0f);
        if (c < 48) hbuf[pt][np15 * 4 + d_p] = h;
    }
    WAVE_LDS_FENCE();   // hbuf RAW (same wave, validated R4)

    float pv[NSAMP];

    // ---- stage 1: per-(n,c) relation input into LDS; v+pe kept in regs ----
#pragma unroll
    for (int n = 0; n < NSAMP; n++) {
        float4 hb = *((const float4*)&hbuf[pt][n * 4]);
        float pe = fmaf(hb.z, wp2c2, fmaf(hb.y, wp2c1, fmaf(hb.x, wp2c0, bp2c)));
        float kk = lo2f(kvw[n]);
        float vv = hi2f(kvw[n]);
        wvbuf[pt][n * 68 + c] = fmaxf(fmaf(kk - qq + pe, g1c, bb1c), 0.0f);
        pv[n] = vv + pe;
    }
    __syncthreads();

    // ---- stage 2 (merged reps, f32x2 packed): a[n][s], a[n+8][s] ----
    const int s2s = c & 7, s2n = c >> 3;
    f32x2 a0v = {cw[OFF_BA + s2s], 0.0f};
    f32x2 a1v = a0v;
    const float4* waT4 = (const float4*)(cw + OFF_WAT + s2s * 64);
#pragma unroll
    for (int c4 = 0; c4 < 16; c4++) {
        float4 wa  = waT4[c4];
        float4 w40 = *((const float4*)&wvbuf[pt][s2n * 68 + c4 * 4]);
        float4 w41 = *((const float4*)&wvbuf[pt][(s2n + 8) * 68 + c4 * 4]);
        f32x2 waA = {wa.x, wa.y},  waB = {wa.z, wa.w};
        f32x2 p0A = {w40.x, w40.y}, p0B = {w40.z, w40.w};
        f32x2 p1A = {w41.x, w41.y}, p1B = {w41.z, w41.w};
        a0v += p0A * waA;  a0v += p0B * waB;
        a1v += p1A * waA;  a1v += p1B * waB;
    }
    {
        float a0 = a0v.x + a0v.y, a1 = a1v.x + a1v.y;
        float g2s = cw[OFF_G2 + s2s] * rs, bb2s = cw[OFF_BB2 + s2s];
        tbbuf[pt][s2n * 8 + s2s]       = fmaxf(fmaf(a0, g2s, bb2s), 0.0f);
        tbbuf[pt][(s2n + 8) * 8 + s2s] = fmaxf(fmaf(a1, g2s, bb2s), 0.0f);
    }
    __syncthreads();

    // ---- stage 3 (merged reps, f32x2 packed): logits in registers ----
    f32x2 w2av = {cw[OFF_BW + s2s], 0.0f};
    f32x2 w2bv = w2av;
    {
        float4 wb0 = *(const float4*)(cw + OFF_WBT + s2s * 8);
        float4 wb1 = *(const float4*)(cw + OFF_WBT + s2s * 8 + 4);
        float4 t00 = *((const float4*)&tbbuf[pt][s2n * 8]);
        float4 t01 = *((const float4*)&tbbuf[pt][s2n * 8 + 4]);
        float4 t10 = *((const float4*)&tbbuf[pt][(s2n + 8) * 8]);
        float4 t11 = *((const float4*)&tbbuf[pt][(s2n + 8) * 8 + 4]);
        f32x2 b0 = {wb0.x, wb0.y}, b1 = {wb0.z, wb0.w};
        f32x2 b2 = {wb1.x, wb1.y}, b3 = {wb1.z, wb1.w};
        f32x2 u0 = {t00.x, t00.y}, u1 = {t00.z, t00.w};
        f32x2 u2 = {t01.x, t01.y}, u3 = {t01.z, t01.w};
        f32x2 v0 = {t10.x, t10.y}, v1 = {t10.z, t10.w};
        f32x2 v2 = {t11.x, t11.y}, v3 = {t11.z, t11.w};
        w2av += u0 * b0;  w2av += u1 * b1;  w2av += u2 * b2;  w2av += u3 * b3;
        w2bv += v0 * b0;  w2bv += v1 * b1;  w2bv += v2 * b2;  w2bv += v3 * b3;
    }
    float w2a = w2av.x + w2av.y;
    float w2b = w2bv.x + w2bv.y;

    // ---- stage 4: softmax over n per channel t, straight from registers ----
    {
        float m = fmaxf(w2a, w2b);
        m = fmaxf(m, __shfl_xor(m, 8, 64));
        m = fmaxf(m, __shfl_xor(m, 16, 64));
        m = fmaxf(m, __shfl_xor(m, 32, 64));
        float e0 = __expf(w2a - m), e1 = __expf(w2b - m);
        float s = e0 + e1;
        s += __shfl_xor(s, 8, 64);
        s += __shfl_xor(s, 16, 64);
        s += __shfl_xor(s, 32, 64);
        float inv = 1.0f / s;
        w2buf[pt][s2n * 8 + s2s]       = e0 * inv;
        w2buf[pt][(s2n + 8) * 8 + s2s] = e1 * inv;
    }
    __syncthreads();

    // ---- stage 5: out[c] = sum_n pv[n] * w[n][c&7]  (f32x2 packed) ----
    f32x2 ov = {0.0f, 0.0f};
#pragma unroll
    for (int n = 0; n < NSAMP; n += 2) {
        f32x2 pvp = {pv[n], pv[n + 1]};
        f32x2 wp  = {w2buf[pt][n * 8 + s2s], w2buf[pt][(n + 1) * 8 + s2s]};
        ov += pvp * wp;
    }
    float o = ov.x + ov.y;
    if (isf32) ((float*)OUT)[(size_t)i * 64 + c] = o;
    else       ((__hip_bfloat16*)OUT)[(size_t)i * 64 + c] = __float2bfloat16(o);
}

// ---------------------------------------------------------------------------
extern "C" void kernel_launch(void* const* d_in, const int* in_sizes, int n_in,
                              void* d_out, int out_size, void* d_ws, size_t ws_size,
                              hipStream_t stream)
{
    const u16* p   = (const u16*)d_in[0];
    const u16* x   = (const u16*)d_in[1];
    const int* idx = (const int*)d_in[2];

    // workspace layout: cw 16KB + Q 25.6MB + KV 25.6MB ≈ 51.2 MB
    float* cw = (float*)d_ws;                   // 16 KB
    float* Q  = cw + CW_PAD;                    // N*64 f32 = 25.6 MB
    u32*   KV = (u32*)(Q + (size_t)N_PTS * 64); // N*64 u32 = 25.6 MB

    qkv_mfma_kernel<<<1250, 256, 0, stream>>>(
        x,
        d_in[3],  d_in[4],  d_in[5],  d_in[6],  d_in[7],  d_in[8],
        d_in[9],  d_in[10], d_in[11], d_in[12], d_in[13], d_in[14],
        d_in[15], d_in[16], d_in[17], d_in[18], d_in[19], d_in[20],
        d_in[21], d_in[22], cw, Q, KV);                    // 1250*5*16 = 100000
    attn_kernel<<<N_PTS / 4, 256, 0, stream>>>(p, idx, x, cw, Q, KV, d_out);
}

// Round 10
// 354.594 us; speedup vs baseline: 1.0490x; 1.0179x over previous
//
#include <hip/hip_runtime.h>
#include <hip/hip_bf16.h>

typedef unsigned int u32;
typedef unsigned short u16;
typedef __attribute__((ext_vector_type(8))) short short8;   // 8 bf16 (4 VGPRs)
typedef __attribute__((ext_vector_type(4))) float f32x4;    // MFMA C/D
typedef __attribute__((ext_vector_type(2))) float f32x2;    // v_pk_fma_f32 operand

#define N_PTS 100000
#define NSAMP 16

__device__ __forceinline__ float lo2f(u32 u){ return __uint_as_float(u << 16); }
__device__ __forceinline__ float hi2f(u32 u){ return __uint_as_float(u & 0xffff0000u); }
__device__ __forceinline__ float us2f(u16 u){ return __uint_as_float(((u32)u) << 16); }

// round-to-nearest-even f32 -> bf16 bits (finite values only)
__device__ __forceinline__ u16 f2bf(float f) {
    u32 u = __float_as_uint(f);
    return (u16)((u + 0x7fffu + ((u >> 16) & 1u)) >> 16);
}
__device__ __forceinline__ u32 pack2(float k, float v) {
    return (u32)f2bf(k) | ((u32)f2bf(v) << 16);
}

// float readlane: __builtin_amdgcn_readlane is int(int,int); MUST bitcast.
// (R9 failed 0.69 absmax from the silent float->int VALUE conversion.)
__device__ __forceinline__ float readlane_f(float v, int lane) {
    return __uint_as_float(__builtin_amdgcn_readlane(__float_as_uint(v), lane));
}

// Runtime input-dtype probe (must be called by ALL threads of the block).
__device__ __forceinline__ bool detect_f32(const u16* __restrict__ xprobe) {
    float f = us2f(xprobe[(threadIdx.x & 63) * 2]);
    int cnt = __syncthreads_count(fabsf(f) > 1024.0f ? 1 : 0);
    return cnt >= 8;
}

// generic raw-weight element load (fp32 or bf16 source)
__device__ __forceinline__ float rawf(const void* s, int i, bool isf32) {
    return isf32 ? ((const float*)s)[i] : us2f(((const u16*)s)[i]);
}

// canonical fp32 weight-block offsets (floats) — written by qkv block 0,
// consumed by attn (stream-ordered).
#define OFF_WP1  0
#define OFF_BP1  12
#define OFF_GP   16
#define OFF_BP   20
#define OFF_WP2  24
#define OFF_BP2  216
#define OFF_G1   280
#define OFF_BB1  344
#define OFF_BA   408
#define OFF_G2   416
#define OFF_BB2  424
#define OFF_BW   432
#define OFF_WAT  448     /* WaT[s][c] : 8 x 64 f32 (transposed Wa) */
#define OFF_WBT  960     /* WbT[t][s] : 8 x 8  f32 (transposed Wb) */
#define CW_PAD   4096    /* pad to 16 KB of floats */

// ---------------------------------------------------------------------------
// K1: MFMA QKV projection + (block 0) attn-weight canonicalization.
// (unchanged from round 8 — passing)
// ---------------------------------------------------------------------------
#define QKV_TPB 5
__global__ __launch_bounds__(256) void qkv_mfma_kernel(
    const u16* __restrict__ xraw,
    const void* s0,  const void* s1,  const void* s2,  const void* s3,
    const void* s4,  const void* s5,  const void* s6,  const void* s7,
    const void* s8,  const void* s9,  const void* s10, const void* s11,
    const void* s12, const void* s13, const void* s14, const void* s15,
    const void* s16, const void* s17, const void* s18, const void* s19,
    float* __restrict__ cw,
    float* __restrict__ Q, u32* __restrict__ KV)
{
    bool isf32 = detect_f32(xraw);
    const int w   = threadIdx.x >> 6;
    const int l   = threadIdx.x & 63;
    const int col = l & 15;
    const int g   = l >> 4;

    // ---- block 0: write attn's canonical weight block ----
    if (blockIdx.x == 0) {
        const void* srcs[12] = {s6,s7,s8,s9,s10,s11,s12,s13,s15,s16,s17,s19};
        const int   sizes[12]= {9,3,3,3,192,64,64,64,8,8,8,8};
        const int   offs[12] = {OFF_WP1,OFF_BP1,OFF_GP,OFF_BP,OFF_WP2,OFF_BP2,
                                OFF_G1,OFF_BB1,OFF_BA,OFF_G2,OFF_BB2,OFF_BW};
        int tid = threadIdx.x;
        for (int a = 0; a < 12; a++)
            for (int k = tid; k < sizes[a]; k += 256)
                cw[offs[a] + k] = rawf(srcs[a], k, isf32);
        // WaT[s][c] = Wa[c][s] ; WbT[t][s] = Wb[s][t]
        for (int t = tid; t < 512 + 64; t += 256) {
            if (t < 512) {
                int s = t >> 6, cc = t & 63;
                cw[OFF_WAT + s * 64 + cc] = rawf(s14, cc * 8 + s, isf32);
            } else {
                int r = t - 512;
                int tt = r >> 3, ss = r & 7;
                cw[OFF_WBT + tt * 8 + ss] = rawf(s18, ss * 8 + tt, isf32);
            }
        }
    }

    // ---- build B fragments (weights) in registers: hi/lo bf16 planes ----
    const void* wsrc[3] = {s0, s2, s4};
    short8 bh[3][2], bl[3][2];
#pragma unroll
    for (int m = 0; m < 3; m++)
#pragma unroll
        for (int kh = 0; kh < 2; kh++)
#pragma unroll
            for (int j = 0; j < 8; j++) {
                float wv_ = rawf(wsrc[m], (kh * 32 + g * 8 + j) * 64 + w * 16 + col, isf32);
                u16 hb = f2bf(wv_);
                bh[m][kh][j] = (short)hb;
                bl[m][kh][j] = (short)f2bf(wv_ - us2f(hb));
            }
    const float bqc = rawf(s1, w * 16 + col, isf32);
    const float bkc = rawf(s3, w * 16 + col, isf32);
    const float bvc = rawf(s5, w * 16 + col, isf32);

#define LOAD_A(IT, AH, AL)                                                        \
    {                                                                             \
        const int M0_ = (blockIdx.x * QKV_TPB + (IT)) * 16;                       \
        if (isf32) {                                                              \
            const float4* xf = (const float4*)xraw;                               \
            _Pragma("unroll")                                                     \
            for (int kh = 0; kh < 2; kh++) {                                      \
                float4 f0 = xf[(size_t)(M0_ + col) * 16 + kh * 8 + g * 2];        \
                float4 f1 = xf[(size_t)(M0_ + col) * 16 + kh * 8 + g * 2 + 1];    \
                float ff[8] = {f0.x, f0.y, f0.z, f0.w, f1.x, f1.y, f1.z, f1.w};   \
                _Pragma("unroll")                                                 \
                for (int j = 0; j < 8; j++) {                                     \
                    u16 hb_ = f2bf(ff[j]);                                        \
                    AH[kh][j] = (short)hb_;                                       \
                    AL[kh][j] = (short)f2bf(ff[j] - us2f(hb_));                   \
                }                                                                 \
            }                                                                     \
        } else {                                                                  \
            const short8* xb = (const short8*)xraw;                               \
            _Pragma("unroll")                                                     \
            for (int kh = 0; kh < 2; kh++)                                        \
                AH[kh] = xb[(size_t)(M0_ + col) * 8 + kh * 4 + g];                \
        }                                                                         \
    }

    short8 ahA[2], alA[2], ahB[2], alB[2];
    LOAD_A(0, ahA, alA);

#pragma unroll
    for (int it = 0; it < QKV_TPB; it++) {
        short8 (&ah)[2] = (it & 1) ? ahB : ahA;
        short8 (&al)[2] = (it & 1) ? alB : alA;
        short8 (&ahN)[2] = (it & 1) ? ahA : ahB;
        short8 (&alN)[2] = (it & 1) ? alA : alB;
        if (it + 1 < QKV_TPB) LOAD_A(it + 1, ahN, alN);

        const int M0 = (blockIdx.x * QKV_TPB + it) * 16;
        f32x4 aQ = {bqc, bqc, bqc, bqc};
        f32x4 aK = {bkc, bkc, bkc, bkc};
        f32x4 aV = {bvc, bvc, bvc, bvc};

#pragma unroll
        for (int kh = 0; kh < 2; kh++) {
            aQ = __builtin_amdgcn_mfma_f32_16x16x32_bf16(ah[kh], bh[0][kh], aQ, 0, 0, 0);
            aK = __builtin_amdgcn_mfma_f32_16x16x32_bf16(ah[kh], bh[1][kh], aK, 0, 0, 0);
            aV = __builtin_amdgcn_mfma_f32_16x16x32_bf16(ah[kh], bh[2][kh], aV, 0, 0, 0);
            aQ = __builtin_amdgcn_mfma_f32_16x16x32_bf16(ah[kh], bl[0][kh], aQ, 0, 0, 0);
            aK = __builtin_amdgcn_mfma_f32_16x16x32_bf16(ah[kh], bl[1][kh], aK, 0, 0, 0);
            aV = __builtin_amdgcn_mfma_f32_16x16x32_bf16(ah[kh], bl[2][kh], aV, 0, 0, 0);
            if (isf32) {
                aQ = __builtin_amdgcn_mfma_f32_16x16x32_bf16(al[kh], bh[0][kh], aQ, 0, 0, 0);
                aK = __builtin_amdgcn_mfma_f32_16x16x32_bf16(al[kh], bh[1][kh], aK, 0, 0, 0);
                aV = __builtin_amdgcn_mfma_f32_16x16x32_bf16(al[kh], bh[2][kh], aV, 0, 0, 0);
            }
        }

#pragma unroll
        for (int r = 0; r < 4; r++) {
            int row = M0 + g * 4 + r;
            Q [(size_t)row * 64 + w * 16 + col] = aQ[r];
            KV[(size_t)row * 64 + w * 16 + col] = pack2(aK[r], aV[r]);
        }
    }
#undef LOAD_A
}

// ---------------------------------------------------------------------------
// K2: fused attention — round 10 = round 9 with the readlane bitcast fix.
// R4-style scheduling (no burst fence, __syncthreads barriers) + merged
// stage-2/3 reps + WaT/WbT float4 weights + pk-fma + register logits ->
// shfl_xor softmax + h broadcast via readlane_f (no hbuf LDS round-trip).
// ---------------------------------------------------------------------------
__global__ __launch_bounds__(256) void attn_kernel(
    const u16* __restrict__ P, const int* __restrict__ IDX,
    const u16* __restrict__ xprobe, const float* __restrict__ cw,
    const float* __restrict__ Q, const u32* __restrict__ KV,
    void* __restrict__ OUT)
{
    __shared__ __align__(16) float wvbuf[4][NSAMP * 68];  // relu(bn1(w)), stride 68
    __shared__ __align__(16) float tbbuf[4][NSAMP * 8];   // relu(bn2(.@Wa+ba))
    __shared__ __align__(16) float w2buf[4][NSAMP * 8];   // softmax weights

    bool isf32 = detect_f32(xprobe);

    const int pt = threadIdx.x >> 6;
    const int c  = threadIdx.x & 63;
    const int i  = blockIdx.x * 4 + pt;        // grid*4 == N_PTS exactly
    const float rs = 1.0f / sqrtf(1.0f + 1e-5f);

    // ---- neighbor indices (lane n<16 holds j_n), then all 16 gathers ----
    const int jv = IDX[(size_t)i * NSAMP + (c & 15)];

    u32 kvw[NSAMP];
    const u32* KVc = KV + c;
#pragma unroll
    for (int n = 0; n < NSAMP; n++) {
        int j = __builtin_amdgcn_readlane(jv, n);   // int readlane: OK as-is
        kvw[n] = KVc[(size_t)j << 6];
    }

    const float qq = Q[(size_t)i * 64 + c];

    // ---- distributed h-MLP: lane (n,d) = (c/3, c%3) computes h[n][d] ----
    const float* Pf = (const float*)P;
    const int n_p  = c / 3;
    const int d_p  = c - n_p * 3;
    const int np15 = n_p & 15;
    const int j_p  = __shfl(jv, np15, 64);
    float pj, pid;
    if (isf32) { pj = Pf[(size_t)j_p * 3 + d_p]; pid = Pf[(size_t)i * 3 + d_p]; }
    else       { pj = us2f(P[(size_t)j_p * 3 + d_p]); pid = us2f(P[(size_t)i * 3 + d_p]); }
    const float pr = pj - pid;
    const int lb = np15 * 3;
    const float prD0 = __shfl(pr, lb + 0, 64);
    const float prD1 = __shfl(pr, lb + 1, 64);
    const float prD2 = __shfl(pr, lb + 2, 64);
    float hval;
    {
        float gd  = cw[OFF_GP + d_p] * rs;
        float w0s = cw[OFF_WP1 + 0 * 3 + d_p] * gd;
        float w1s = cw[OFF_WP1 + 1 * 3 + d_p] * gd;
        float w2s = cw[OFF_WP1 + 2 * 3 + d_p] * gd;
        float bs  = cw[OFF_BP1 + d_p] * gd + cw[OFF_BP + d_p];
        hval = fmaxf(fmaf(prD2, w2s, fmaf(prD1, w1s, fmaf(prD0, w0s, bs))), 0.0f);
    }

    // per-lane channel constants (L1-hot)
    const float wp2c0 = cw[OFF_WP2 + 0 * 64 + c];
    const float wp2c1 = cw[OFF_WP2 + 1 * 64 + c];
    const float wp2c2 = cw[OFF_WP2 + 2 * 64 + c];
    const float bp2c  = cw[OFF_BP2 + c];
    const float g1c   = cw[OFF_G1  + c] * rs;
    const float bb1c  = cw[OFF_BB1 + c];

    float pv[NSAMP];

    // ---- stage 1: pe via readlane_f broadcast of h (no LDS round-trip) ----
#pragma unroll
    for (int n = 0; n < NSAMP; n++) {
        float h0 = readlane_f(hval, n * 3 + 0);
        float h1 = readlane_f(hval, n * 3 + 1);
        float h2 = readlane_f(hval, n * 3 + 2);
        float pe = fmaf(h2, wp2c2, fmaf(h1, wp2c1, fmaf(h0, wp2c0, bp2c)));
        float kk = lo2f(kvw[n]);
        float vv = hi2f(kvw[n]);
        wvbuf[pt][n * 68 + c] = fmaxf(fmaf(kk - qq + pe, g1c, bb1c), 0.0f);
        pv[n] = vv + pe;
    }
    __syncthreads();

    // ---- stage 2 (merged reps, f32x2 packed): a[n][s], a[n+8][s] ----
    const int s2s = c & 7, s2n = c >> 3;
    f32x2 a0v = {cw[OFF_BA + s2s], 0.0f};
    f32x2 a1v = a0v;
    const float4* waT4 = (const float4*)(cw + OFF_WAT + s2s * 64);
#pragma unroll
    for (int c4 = 0; c4 < 16; c4++) {
        float4 wa  = waT4[c4];
        float4 w40 = *((const float4*)&wvbuf[pt][s2n * 68 + c4 * 4]);
        float4 w41 = *((const float4*)&wvbuf[pt][(s2n + 8) * 68 + c4 * 4]);
        f32x2 waA = {wa.x, wa.y},  waB = {wa.z, wa.w};
        f32x2 p0A = {w40.x, w40.y}, p0B = {w40.z, w40.w};
        f32x2 p1A = {w41.x, w41.y}, p1B = {w41.z, w41.w};
        a0v += p0A * waA;  a0v += p0B * waB;
        a1v += p1A * waA;  a1v += p1B * waB;
    }
    {
        float a0 = a0v.x + a0v.y, a1 = a1v.x + a1v.y;
        float g2s = cw[OFF_G2 + s2s] * rs, bb2s = cw[OFF_BB2 + s2s];
        tbbuf[pt][s2n * 8 + s2s]       = fmaxf(fmaf(a0, g2s, bb2s), 0.0f);
        tbbuf[pt][(s2n + 8) * 8 + s2s] = fmaxf(fmaf(a1, g2s, bb2s), 0.0f);
    }
    __syncthreads();

    // ---- stage 3 (merged reps, f32x2 packed): logits in registers ----
    f32x2 w2av = {cw[OFF_BW + s2s], 0.0f};
    f32x2 w2bv = w2av;
    {
        float4 wb0 = *(const float4*)(cw + OFF_WBT + s2s * 8);
        float4 wb1 = *(const float4*)(cw + OFF_WBT + s2s * 8 + 4);
        float4 t00 = *((const float4*)&tbbuf[pt][s2n * 8]);
        float4 t01 = *((const float4*)&tbbuf[pt][s2n * 8 + 4]);
        float4 t10 = *((const float4*)&tbbuf[pt][(s2n + 8) * 8]);
        float4 t11 = *((const float4*)&tbbuf[pt][(s2n + 8) * 8 + 4]);
        f32x2 b0 = {wb0.x, wb0.y}, b1 = {wb0.z, wb0.w};
        f32x2 b2 = {wb1.x, wb1.y}, b3 = {wb1.z, wb1.w};
        f32x2 u0 = {t00.x, t00.y}, u1 = {t00.z, t00.w};
        f32x2 u2 = {t01.x, t01.y}, u3 = {t01.z, t01.w};
        f32x2 v0 = {t10.x, t10.y}, v1 = {t10.z, t10.w};
        f32x2 v2 = {t11.x, t11.y}, v3 = {t11.z, t11.w};
        w2av += u0 * b0;  w2av += u1 * b1;  w2av += u2 * b2;  w2av += u3 * b3;
        w2bv += v0 * b0;  w2bv += v1 * b1;  w2bv += v2 * b2;  w2bv += v3 * b3;
    }
    float w2a = w2av.x + w2av.y;
    float w2b = w2bv.x + w2bv.y;

    // ---- stage 4: softmax over n per channel t, straight from registers ----
    {
        float m = fmaxf(w2a, w2b);
        m = fmaxf(m, __shfl_xor(m, 8, 64));
        m = fmaxf(m, __shfl_xor(m, 16, 64));
        m = fmaxf(m, __shfl_xor(m, 32, 64));
        float e0 = __expf(w2a - m), e1 = __expf(w2b - m);
        float s = e0 + e1;
        s += __shfl_xor(s, 8, 64);
        s += __shfl_xor(s, 16, 64);
        s += __shfl_xor(s, 32, 64);
        float inv = 1.0f / s;
        w2buf[pt][s2n * 8 + s2s]       = e0 * inv;
        w2buf[pt][(s2n + 8) * 8 + s2s] = e1 * inv;
    }
    __syncthreads();

    // ---- stage 5: out[c] = sum_n pv[n] * w[n][c&7]  (f32x2 packed) ----
    f32x2 ov = {0.0f, 0.0f};
#pragma unroll
    for (int n = 0; n < NSAMP; n += 2) {
        f32x2 pvp = {pv[n], pv[n + 1]};
        f32x2 wp  = {w2buf[pt][n * 8 + s2s], w2buf[pt][(n + 1) * 8 + s2s]};
        ov += pvp * wp;
    }
    float o = ov.x + ov.y;
    if (isf32) ((float*)OUT)[(size_t)i * 64 + c] = o;
    else       ((__hip_bfloat16*)OUT)[(size_t)i * 64 + c] = __float2bfloat16(o);
}

// ---------------------------------------------------------------------------
extern "C" void kernel_launch(void* const* d_in, const int* in_sizes, int n_in,
                              void* d_out, int out_size, void* d_ws, size_t ws_size,
                              hipStream_t stream)
{
    const u16* p   = (const u16*)d_in[0];
    const u16* x   = (const u16*)d_in[1];
    const int* idx = (const int*)d_in[2];

    // workspace layout: cw 16KB + Q 25.6MB + KV 25.6MB ≈ 51.2 MB
    float* cw = (float*)d_ws;                   // 16 KB
    float* Q  = cw + CW_PAD;                    // N*64 f32 = 25.6 MB
    u32*   KV = (u32*)(Q + (size_t)N_PTS * 64); // N*64 u32 = 25.6 MB

    qkv_mfma_kernel<<<1250, 256, 0, stream>>>(
        x,
        d_in[3],  d_in[4],  d_in[5],  d_in[6],  d_in[7],  d_in[8],
        d_in[9],  d_in[10], d_in[11], d_in[12], d_in[13], d_in[14],
        d_in[15], d_in[16], d_in[17], d_in[18], d_in[19], d_in[20],
        d_in[21], d_in[22], cw, Q, KV);                    // 1250*5*16 = 100000
    attn_kernel<<<N_PTS / 4, 256, 0, stream>>>(p, idx, x, cw, Q, KV, d_out);
}

// Round 11
// 309.169 us; speedup vs baseline: 1.2032x; 1.1469x over previous
//
#include <hip/hip_runtime.h>
#include <hip/hip_bf16.h>

typedef unsigned int u32;
typedef unsigned short u16;
typedef __attribute__((ext_vector_type(8))) short short8;   // 8 bf16 (4 VGPRs)
typedef __attribute__((ext_vector_type(4))) float f32x4;    // MFMA C/D
typedef __attribute__((ext_vector_type(2))) float f32x2;    // v_pk_fma_f32 operand

#define N_PTS 100000
#define NSAMP 16

__device__ __forceinline__ float lo2f(u32 u){ return __uint_as_float(u << 16); }
__device__ __forceinline__ float hi2f(u32 u){ return __uint_as_float(u & 0xffff0000u); }
__device__ __forceinline__ float us2f(u16 u){ return __uint_as_float(((u32)u) << 16); }

// round-to-nearest-even f32 -> bf16 bits (finite values only)
__device__ __forceinline__ u16 f2bf(float f) {
    u32 u = __float_as_uint(f);
    return (u16)((u + 0x7fffu + ((u >> 16) & 1u)) >> 16);
}
__device__ __forceinline__ u32 pack2(float k, float v) {
    return (u32)f2bf(k) | ((u32)f2bf(v) << 16);
}

// wave-local LDS RAW fence. The "memory" clobber ALSO pins global loads
// above it (they cannot sink past) — this is the R4-proven mechanism that
// keeps the gather burst issued up-front (R9/R10 lost it -> serialization).
#define WAVE_LDS_FENCE() asm volatile("s_waitcnt lgkmcnt(0)" ::: "memory")

// Runtime input-dtype probe (must be called by ALL threads of the block).
__device__ __forceinline__ bool detect_f32(const u16* __restrict__ xprobe) {
    float f = us2f(xprobe[(threadIdx.x & 63) * 2]);
    int cnt = __syncthreads_count(fabsf(f) > 1024.0f ? 1 : 0);
    return cnt >= 8;
}

// generic raw-weight element load (fp32 or bf16 source)
__device__ __forceinline__ float rawf(const void* s, int i, bool isf32) {
    return isf32 ? ((const float*)s)[i] : us2f(((const u16*)s)[i]);
}

// canonical fp32 weight-block offsets (floats) — written by qkv block 0,
// consumed by attn (stream-ordered).
#define OFF_WP1  0
#define OFF_BP1  12
#define OFF_GP   16
#define OFF_BP   20
#define OFF_WP2  24
#define OFF_BP2  216
#define OFF_G1   280
#define OFF_BB1  344
#define OFF_BA   408
#define OFF_G2   416
#define OFF_BB2  424
#define OFF_BW   432
#define OFF_WAT  448     /* WaT[s][c] : 8 x 64 f32 (transposed Wa) */
#define OFF_WBT  960     /* WbT[t][s] : 8 x 8  f32 (transposed Wb) */
#define CW_PAD   4096    /* pad to 16 KB of floats */

// ---------------------------------------------------------------------------
// K1: MFMA QKV projection + (block 0) attn-weight canonicalization.
// (unchanged from round 8/10 — passing)
// ---------------------------------------------------------------------------
#define QKV_TPB 5
__global__ __launch_bounds__(256) void qkv_mfma_kernel(
    const u16* __restrict__ xraw,
    const void* s0,  const void* s1,  const void* s2,  const void* s3,
    const void* s4,  const void* s5,  const void* s6,  const void* s7,
    const void* s8,  const void* s9,  const void* s10, const void* s11,
    const void* s12, const void* s13, const void* s14, const void* s15,
    const void* s16, const void* s17, const void* s18, const void* s19,
    float* __restrict__ cw,
    float* __restrict__ Q, u32* __restrict__ KV)
{
    bool isf32 = detect_f32(xraw);
    const int w   = threadIdx.x >> 6;
    const int l   = threadIdx.x & 63;
    const int col = l & 15;
    const int g   = l >> 4;

    // ---- block 0: write attn's canonical weight block ----
    if (blockIdx.x == 0) {
        const void* srcs[12] = {s6,s7,s8,s9,s10,s11,s12,s13,s15,s16,s17,s19};
        const int   sizes[12]= {9,3,3,3,192,64,64,64,8,8,8,8};
        const int   offs[12] = {OFF_WP1,OFF_BP1,OFF_GP,OFF_BP,OFF_WP2,OFF_BP2,
                                OFF_G1,OFF_BB1,OFF_BA,OFF_G2,OFF_BB2,OFF_BW};
        int tid = threadIdx.x;
        for (int a = 0; a < 12; a++)
            for (int k = tid; k < sizes[a]; k += 256)
                cw[offs[a] + k] = rawf(srcs[a], k, isf32);
        // WaT[s][c] = Wa[c][s] ; WbT[t][s] = Wb[s][t]
        for (int t = tid; t < 512 + 64; t += 256) {
            if (t < 512) {
                int s = t >> 6, cc = t & 63;
                cw[OFF_WAT + s * 64 + cc] = rawf(s14, cc * 8 + s, isf32);
            } else {
                int r = t - 512;
                int tt = r >> 3, ss = r & 7;
                cw[OFF_WBT + tt * 8 + ss] = rawf(s18, ss * 8 + tt, isf32);
            }
        }
    }

    // ---- build B fragments (weights) in registers: hi/lo bf16 planes ----
    const void* wsrc[3] = {s0, s2, s4};
    short8 bh[3][2], bl[3][2];
#pragma unroll
    for (int m = 0; m < 3; m++)
#pragma unroll
        for (int kh = 0; kh < 2; kh++)
#pragma unroll
            for (int j = 0; j < 8; j++) {
                float wv_ = rawf(wsrc[m], (kh * 32 + g * 8 + j) * 64 + w * 16 + col, isf32);
                u16 hb = f2bf(wv_);
                bh[m][kh][j] = (short)hb;
                bl[m][kh][j] = (short)f2bf(wv_ - us2f(hb));
            }
    const float bqc = rawf(s1, w * 16 + col, isf32);
    const float bkc = rawf(s3, w * 16 + col, isf32);
    const float bvc = rawf(s5, w * 16 + col, isf32);

#define LOAD_A(IT, AH, AL)                                                        \
    {                                                                             \
        const int M0_ = (blockIdx.x * QKV_TPB + (IT)) * 16;                       \
        if (isf32) {                                                              \
            const float4* xf = (const float4*)xraw;                               \
            _Pragma("unroll")                                                     \
            for (int kh = 0; kh < 2; kh++) {                                      \
                float4 f0 = xf[(size_t)(M0_ + col) * 16 + kh * 8 + g * 2];        \
                float4 f1 = xf[(size_t)(M0_ + col) * 16 + kh * 8 + g * 2 + 1];    \
                float ff[8] = {f0.x, f0.y, f0.z, f0.w, f1.x, f1.y, f1.z, f1.w};   \
                _Pragma("unroll")                                                 \
                for (int j = 0; j < 8; j++) {                                     \
                    u16 hb_ = f2bf(ff[j]);                                        \
                    AH[kh][j] = (short)hb_;                                       \
                    AL[kh][j] = (short)f2bf(ff[j] - us2f(hb_));                   \
                }                                                                 \
            }                                                                     \
        } else {                                                                  \
            const short8* xb = (const short8*)xraw;                               \
            _Pragma("unroll")                                                     \
            for (int kh = 0; kh < 2; kh++)                                        \
                AH[kh] = xb[(size_t)(M0_ + col) * 8 + kh * 4 + g];                \
        }                                                                         \
    }

    short8 ahA[2], alA[2], ahB[2], alB[2];
    LOAD_A(0, ahA, alA);

#pragma unroll
    for (int it = 0; it < QKV_TPB; it++) {
        short8 (&ah)[2] = (it & 1) ? ahB : ahA;
        short8 (&al)[2] = (it & 1) ? alB : alA;
        short8 (&ahN)[2] = (it & 1) ? ahA : ahB;
        short8 (&alN)[2] = (it & 1) ? alA : alB;
        if (it + 1 < QKV_TPB) LOAD_A(it + 1, ahN, alN);

        const int M0 = (blockIdx.x * QKV_TPB + it) * 16;
        f32x4 aQ = {bqc, bqc, bqc, bqc};
        f32x4 aK = {bkc, bkc, bkc, bkc};
        f32x4 aV = {bvc, bvc, bvc, bvc};

#pragma unroll
        for (int kh = 0; kh < 2; kh++) {
            aQ = __builtin_amdgcn_mfma_f32_16x16x32_bf16(ah[kh], bh[0][kh], aQ, 0, 0, 0);
            aK = __builtin_amdgcn_mfma_f32_16x16x32_bf16(ah[kh], bh[1][kh], aK, 0, 0, 0);
            aV = __builtin_amdgcn_mfma_f32_16x16x32_bf16(ah[kh], bh[2][kh], aV, 0, 0, 0);
            aQ = __builtin_amdgcn_mfma_f32_16x16x32_bf16(ah[kh], bl[0][kh], aQ, 0, 0, 0);
            aK = __builtin_amdgcn_mfma_f32_16x16x32_bf16(ah[kh], bl[1][kh], aK, 0, 0, 0);
            aV = __builtin_amdgcn_mfma_f32_16x16x32_bf16(ah[kh], bl[2][kh], aV, 0, 0, 0);
            if (isf32) {
                aQ = __builtin_amdgcn_mfma_f32_16x16x32_bf16(al[kh], bh[0][kh], aQ, 0, 0, 0);
                aK = __builtin_amdgcn_mfma_f32_16x16x32_bf16(al[kh], bh[1][kh], aK, 0, 0, 0);
                aV = __builtin_amdgcn_mfma_f32_16x16x32_bf16(al[kh], bh[2][kh], aV, 0, 0, 0);
            }
        }

#pragma unroll
        for (int r = 0; r < 4; r++) {
            int row = M0 + g * 4 + r;
            Q [(size_t)row * 64 + w * 16 + col] = aQ[r];
            KV[(size_t)row * 64 + w * 16 + col] = pack2(aK[r], aV[r]);
        }
    }
#undef LOAD_A
}

// ---------------------------------------------------------------------------
// K2: fused attention — round 11: TWO POINTS PER WAVE.
// R4-proven pinning structure (hbuf + lgkmcnt fence + __syncthreads) at 2x
// width: 32 gathers issued in one pinned burst per wave; per-wave latency
// exposure amortized over two points' work. LDS doubles (~44 KB -> 3
// blocks/CU); __launch_bounds__(256,3) licenses ~170 VGPR so the burst
// stays register-resident (the 36-VGPR schedule was the R6-R10 regression).
// Block = 4 waves x 2 points = 8 points; grid = 12500 exactly.
// ---------------------------------------------------------------------------
__global__ __launch_bounds__(256, 3) void attn_kernel(
    const u16* __restrict__ P, const int* __restrict__ IDX,
    const u16* __restrict__ xprobe, const float* __restrict__ cw,
    const float* __restrict__ Q, const u32* __restrict__ KV,
    void* __restrict__ OUT)
{
    __shared__ __align__(16) float wvbuf[8][NSAMP * 68];  // relu(bn1(w)), stride 68
    __shared__ __align__(16) float tbbuf[8][NSAMP * 8];   // relu(bn2(.@Wa+ba))
    __shared__ __align__(16) float w2buf[8][NSAMP * 8];   // softmax weights
    __shared__ __align__(16) float hbuf[8][NSAMP * 4];    // h[n][d], d<3 used

    bool isf32 = detect_f32(xprobe);

    const int pt  = threadIdx.x >> 6;
    const int c   = threadIdx.x & 63;
    const int i0  = blockIdx.x * 8 + pt * 2;   // grid*8 == N_PTS exactly
    const int i1  = i0 + 1;
    const int sl0 = pt * 2, sl1 = sl0 + 1;     // wave-owned LDS slices
    const float rs = 1.0f / sqrtf(1.0f + 1e-5f);

    // ---- burst: indices + 32 KV gathers + Q + P, all before the fence ----
    const int jv0 = IDX[(size_t)i0 * NSAMP + (c & 15)];
    const int jv1 = IDX[(size_t)i1 * NSAMP + (c & 15)];

    u32 kv0[NSAMP], kv1[NSAMP];
    const u32* KVc = KV + c;
#pragma unroll
    for (int n = 0; n < NSAMP; n++) {
        int j = __builtin_amdgcn_readlane(jv0, n);   // SGPR -> SALU addressing
        kv0[n] = KVc[(size_t)j << 6];
    }
#pragma unroll
    for (int n = 0; n < NSAMP; n++) {
        int j = __builtin_amdgcn_readlane(jv1, n);
        kv1[n] = KVc[(size_t)j << 6];
    }

    const float qq0 = Q[(size_t)i0 * 64 + c];
    const float qq1 = Q[(size_t)i1 * 64 + c];

    // ---- distributed h-MLP for both points: lane (n,d) = (c/3, c%3) ----
    const float* Pf = (const float*)P;
    const int n_p  = c / 3;
    const int d_p  = c - n_p * 3;
    const int np15 = n_p & 15;
    const int jp0  = __shfl(jv0, np15, 64);
    const int jp1  = __shfl(jv1, np15, 64);
    float pj0, pj1, pid0, pid1;
    if (isf32) {
        pj0 = Pf[(size_t)jp0 * 3 + d_p];  pid0 = Pf[(size_t)i0 * 3 + d_p];
        pj1 = Pf[(size_t)jp1 * 3 + d_p];  pid1 = Pf[(size_t)i1 * 3 + d_p];
    } else {
        pj0 = us2f(P[(size_t)jp0 * 3 + d_p]);  pid0 = us2f(P[(size_t)i0 * 3 + d_p]);
        pj1 = us2f(P[(size_t)jp1 * 3 + d_p]);  pid1 = us2f(P[(size_t)i1 * 3 + d_p]);
    }
    const float pr0 = pj0 - pid0, pr1 = pj1 - pid1;
    const int lb = np15 * 3;
    const float pA0 = __shfl(pr0, lb + 0, 64);
    const float pA1 = __shfl(pr0, lb + 1, 64);
    const float pA2 = __shfl(pr0, lb + 2, 64);
    const float pB0 = __shfl(pr1, lb + 0, 64);
    const float pB1 = __shfl(pr1, lb + 1, 64);
    const float pB2 = __shfl(pr1, lb + 2, 64);
    {
        float gd  = cw[OFF_GP + d_p] * rs;
        float w0s = cw[OFF_WP1 + 0 * 3 + d_p] * gd;
        float w1s = cw[OFF_WP1 + 1 * 3 + d_p] * gd;
        float w2s = cw[OFF_WP1 + 2 * 3 + d_p] * gd;
        float bs  = cw[OFF_BP1 + d_p] * gd + cw[OFF_BP + d_p];
        float hA = fmaxf(fmaf(pA2, w2s, fmaf(pA1, w1s, fmaf(pA0, w0s, bs))), 0.0f);
        float hB = fmaxf(fmaf(pB2, w2s, fmaf(pB1, w1s, fmaf(pB0, w0s, bs))), 0.0f);
        if (c < 48) {
            hbuf[sl0][np15 * 4 + d_p] = hA;
            hbuf[sl1][np15 * 4 + d_p] = hB;
        }
    }
    WAVE_LDS_FENCE();   // hbuf RAW (same wave) + pins the 32 gathers above

    // per-lane channel constants (L1-hot)
    const float wp2c0 = cw[OFF_WP2 + 0 * 64 + c];
    const float wp2c1 = cw[OFF_WP2 + 1 * 64 + c];
    const float wp2c2 = cw[OFF_WP2 + 2 * 64 + c];
    const float bp2c  = cw[OFF_BP2 + c];
    const float g1c   = cw[OFF_G1  + c] * rs;
    const float bb1c  = cw[OFF_BB1 + c];

    float pv0[NSAMP], pv1[NSAMP];

    // ---- stage 1 (both points): relation input into LDS; v+pe in regs ----
#pragma unroll
    for (int n = 0; n < NSAMP; n++) {
        float4 hb = *((const float4*)&hbuf[sl0][n * 4]);
        float pe = fmaf(hb.z, wp2c2, fmaf(hb.y, wp2c1, fmaf(hb.x, wp2c0, bp2c)));
        float kk = lo2f(kv0[n]);
        float vv = hi2f(kv0[n]);
        wvbuf[sl0][n * 68 + c] = fmaxf(fmaf(kk - qq0 + pe, g1c, bb1c), 0.0f);
        pv0[n] = vv + pe;
    }
#pragma unroll
    for (int n = 0; n < NSAMP; n++) {
        float4 hb = *((const float4*)&hbuf[sl1][n * 4]);
        float pe = fmaf(hb.z, wp2c2, fmaf(hb.y, wp2c1, fmaf(hb.x, wp2c0, bp2c)));
        float kk = lo2f(kv1[n]);
        float vv = hi2f(kv1[n]);
        wvbuf[sl1][n * 68 + c] = fmaxf(fmaf(kk - qq1 + pe, g1c, bb1c), 0.0f);
        pv1[n] = vv + pe;
    }
    __syncthreads();

    // ---- stage 2 (both points, merged reps, f32x2 packed) ----
    const int s2s = c & 7, s2n = c >> 3;
    f32x2 aA0 = {cw[OFF_BA + s2s], 0.0f};
    f32x2 aA1 = aA0, aB0 = aA0, aB1 = aA0;
    const float4* waT4 = (const float4*)(cw + OFF_WAT + s2s * 64);
#pragma unroll
    for (int c4 = 0; c4 < 16; c4++) {
        float4 wa = waT4[c4];
        f32x2 waA = {wa.x, wa.y}, waB = {wa.z, wa.w};
        float4 rA0 = *((const float4*)&wvbuf[sl0][s2n * 68 + c4 * 4]);
        float4 rA1 = *((const float4*)&wvbuf[sl0][(s2n + 8) * 68 + c4 * 4]);
        float4 rB0 = *((const float4*)&wvbuf[sl1][s2n * 68 + c4 * 4]);
        float4 rB1 = *((const float4*)&wvbuf[sl1][(s2n + 8) * 68 + c4 * 4]);
        f32x2 tA0a = {rA0.x, rA0.y}, tA0b = {rA0.z, rA0.w};
        f32x2 tA1a = {rA1.x, rA1.y}, tA1b = {rA1.z, rA1.w};
        f32x2 tB0a = {rB0.x, rB0.y}, tB0b = {rB0.z, rB0.w};
        f32x2 tB1a = {rB1.x, rB1.y}, tB1b = {rB1.z, rB1.w};
        aA0 += tA0a * waA;  aA0 += tA0b * waB;
        aA1 += tA1a * waA;  aA1 += tA1b * waB;
        aB0 += tB0a * waA;  aB0 += tB0b * waB;
        aB1 += tB1a * waA;  aB1 += tB1b * waB;
    }
    {
        float g2s = cw[OFF_G2 + s2s] * rs, bb2s = cw[OFF_BB2 + s2s];
        tbbuf[sl0][s2n * 8 + s2s]       = fmaxf(fmaf(aA0.x + aA0.y, g2s, bb2s), 0.0f);
        tbbuf[sl0][(s2n + 8) * 8 + s2s] = fmaxf(fmaf(aA1.x + aA1.y, g2s, bb2s), 0.0f);
        tbbuf[sl1][s2n * 8 + s2s]       = fmaxf(fmaf(aB0.x + aB0.y, g2s, bb2s), 0.0f);
        tbbuf[sl1][(s2n + 8) * 8 + s2s] = fmaxf(fmaf(aB1.x + aB1.y, g2s, bb2s), 0.0f);
    }
    __syncthreads();

    // ---- stage 3 (both points): logits in registers ----
    f32x2 wA0 = {cw[OFF_BW + s2s], 0.0f};
    f32x2 wA1 = wA0, wB0 = wA0, wB1 = wA0;
    {
        float4 wb0 = *(const float4*)(cw + OFF_WBT + s2s * 8);
        float4 wb1 = *(const float4*)(cw + OFF_WBT + s2s * 8 + 4);
        f32x2 b0 = {wb0.x, wb0.y}, b1 = {wb0.z, wb0.w};
        f32x2 b2 = {wb1.x, wb1.y}, b3 = {wb1.z, wb1.w};
#define ACC_LOGIT(ACC, SL, ROW)                                                   \
        {                                                                         \
            float4 t0_ = *((const float4*)&tbbuf[SL][(ROW) * 8]);                 \
            float4 t1_ = *((const float4*)&tbbuf[SL][(ROW) * 8 + 4]);             \
            f32x2 u0_ = {t0_.x, t0_.y}, u1_ = {t0_.z, t0_.w};                     \
            f32x2 u2_ = {t1_.x, t1_.y}, u3_ = {t1_.z, t1_.w};                     \
            ACC += u0_ * b0;  ACC += u1_ * b1;  ACC += u2_ * b2;  ACC += u3_ * b3;\
        }
        ACC_LOGIT(wA0, sl0, s2n)
        ACC_LOGIT(wA1, sl0, s2n + 8)
        ACC_LOGIT(wB0, sl1, s2n)
        ACC_LOGIT(wB1, sl1, s2n + 8)
#undef ACC_LOGIT
    }
    float lA0 = wA0.x + wA0.y, lA1 = wA1.x + wA1.y;
    float lB0 = wB0.x + wB0.y, lB1 = wB1.x + wB1.y;

    // ---- stage 4: softmax per point over n (lanes share s via xor tree) ----
    {
        float m0 = fmaxf(lA0, lA1);
        m0 = fmaxf(m0, __shfl_xor(m0, 8, 64));
        m0 = fmaxf(m0, __shfl_xor(m0, 16, 64));
        m0 = fmaxf(m0, __shfl_xor(m0, 32, 64));
        float e00 = __expf(lA0 - m0), e01 = __expf(lA1 - m0);
        float s0 = e00 + e01;
        s0 += __shfl_xor(s0, 8, 64);
        s0 += __shfl_xor(s0, 16, 64);
        s0 += __shfl_xor(s0, 32, 64);
        float inv0 = 1.0f / s0;
        w2buf[sl0][s2n * 8 + s2s]       = e00 * inv0;
        w2buf[sl0][(s2n + 8) * 8 + s2s] = e01 * inv0;

        float m1 = fmaxf(lB0, lB1);
        m1 = fmaxf(m1, __shfl_xor(m1, 8, 64));
        m1 = fmaxf(m1, __shfl_xor(m1, 16, 64));
        m1 = fmaxf(m1, __shfl_xor(m1, 32, 64));
        float e10 = __expf(lB0 - m1), e11 = __expf(lB1 - m1);
        float s1 = e10 + e11;
        s1 += __shfl_xor(s1, 8, 64);
        s1 += __shfl_xor(s1, 16, 64);
        s1 += __shfl_xor(s1, 32, 64);
        float inv1 = 1.0f / s1;
        w2buf[sl1][s2n * 8 + s2s]       = e10 * inv1;
        w2buf[sl1][(s2n + 8) * 8 + s2s] = e11 * inv1;
    }
    __syncthreads();

    // ---- stage 5 (both points): out[c] = sum_n pv[n] * w[n][c&7] ----
    f32x2 ov0 = {0.0f, 0.0f}, ov1 = {0.0f, 0.0f};
#pragma unroll
    for (int n = 0; n < NSAMP; n += 2) {
        f32x2 p0 = {pv0[n], pv0[n + 1]};
        f32x2 w0 = {w2buf[sl0][n * 8 + s2s], w2buf[sl0][(n + 1) * 8 + s2s]};
        f32x2 p1 = {pv1[n], pv1[n + 1]};
        f32x2 w1 = {w2buf[sl1][n * 8 + s2s], w2buf[sl1][(n + 1) * 8 + s2s]};
        ov0 += p0 * w0;
        ov1 += p1 * w1;
    }
    float o0 = ov0.x + ov0.y;
    float o1 = ov1.x + ov1.y;
    if (isf32) {
        ((float*)OUT)[(size_t)i0 * 64 + c] = o0;
        ((float*)OUT)[(size_t)i1 * 64 + c] = o1;
    } else {
        ((__hip_bfloat16*)OUT)[(size_t)i0 * 64 + c] = __float2bfloat16(o0);
        ((__hip_bfloat16*)OUT)[(size_t)i1 * 64 + c] = __float2bfloat16(o1);
    }
}

// ---------------------------------------------------------------------------
extern "C" void kernel_launch(void* const* d_in, const int* in_sizes, int n_in,
                              void* d_out, int out_size, void* d_ws, size_t ws_size,
                              hipStream_t stream)
{
    const u16* p   = (const u16*)d_in[0];
    const u16* x   = (const u16*)d_in[1];
    const int* idx = (const int*)d_in[2];

    // workspace layout: cw 16KB + Q 25.6MB + KV 25.6MB ≈ 51.2 MB
    float* cw = (float*)d_ws;                   // 16 KB
    float* Q  = cw + CW_PAD;                    // N*64 f32 = 25.6 MB
    u32*   KV = (u32*)(Q + (size_t)N_PTS * 64); // N*64 u32 = 25.6 MB

    qkv_mfma_kernel<<<1250, 256, 0, stream>>>(
        x,
        d_in[3],  d_in[4],  d_in[5],  d_in[6],  d_in[7],  d_in[8],
        d_in[9],  d_in[10], d_in[11], d_in[12], d_in[13], d_in[14],
        d_in[15], d_in[16], d_in[17], d_in[18], d_in[19], d_in[20],
        d_in[21], d_in[22], cw, Q, KV);                    // 1250*5*16 = 100000
    attn_kernel<<<N_PTS / 8, 256, 0, stream>>>(p, idx, x, cw, Q, KV, d_out);
}